// Round 1
// 104.250 us; speedup vs baseline: 1.0917x; 1.0917x over previous
//
#include <hip/hip_runtime.h>
#include <stdint.h>

// FFEdgeCountingAutoencoder4: two "fuzzy logic" layers.
// Randomness: JAX threefry2x32, PARTITIONABLE counter semantics:
//   bits(e) = o0 ^ o1 of threefry(key, (0, e)).   (verified: absmax == 0.0)
// Keys host-side: base=key(42)=(0,42); K_l=tf(base,(0,l));
//   split: k_op=tf(K,(0,0)), k_edge=tf(K,(0,1)).
// Gumbel: u = max(tiny, ((bits>>9)|0x3f800000 as float)-1); g=-log(-log u).
//
// NEW (this round): the argmax comparisons don't need correctly-rounded
// gumbels, only a certified error bound. Fast path: f32 log (atanh form,
// Sterbenz-exact m-1, v_rcp_f32, 3-term poly; certified |abs err on g|
// <= ~2e-4 worst-case incl. u->1 amplification, ~3.5e-5 typical). Guard:
// decide by sign only if |t1-t0| > tau = 1e-3 + 3.1e-5*(|t0|+|t1|)
// (>=5x margin over certified error + f32 add-rounding terms). Otherwise
// fall back to the bit-exact f64-log path (unchanged, reuses the same
// threefry bits). Ties land in the fallback -> argmax tie->0 preserved.

__host__ __device__ inline uint32_t rotl32(uint32_t x, uint32_t d) {
  return (x << d) | (x >> (32u - d));
}

__host__ __device__ inline void threefry2x32(uint32_t k0, uint32_t k1,
                                             uint32_t x0, uint32_t x1,
                                             uint32_t* o0, uint32_t* o1) {
  uint32_t ks0 = k0, ks1 = k1, ks2 = k0 ^ k1 ^ 0x1BD11BDAu;
  x0 += ks0; x1 += ks1;
#define TF_R(r) { x0 += x1; x1 = rotl32(x1, r); x1 ^= x0; }
  TF_R(13u) TF_R(15u) TF_R(26u) TF_R(6u)
  x0 += ks1; x1 += ks2 + 1u;
  TF_R(17u) TF_R(29u) TF_R(16u) TF_R(24u)
  x0 += ks2; x1 += ks0 + 2u;
  TF_R(13u) TF_R(15u) TF_R(26u) TF_R(6u)
  x0 += ks0; x1 += ks1 + 3u;
  TF_R(17u) TF_R(29u) TF_R(16u) TF_R(24u)
  x0 += ks1; x1 += ks2 + 4u;
  TF_R(13u) TF_R(15u) TF_R(26u) TF_R(6u)
  x0 += ks2; x1 += ks0 + 5u;
#undef TF_R
  *o0 = x0; *o1 = x1;
}

__device__ __forceinline__ uint32_t rbits32(uint32_t k0, uint32_t k1,
                                            uint32_t e) {
  uint32_t a, b;
  threefry2x32(k0, k1, 0u, e, &a, &b);
  return a ^ b;
}

// -------- exact path: f64 log for normal positive finite x --------
// (domain: u in [1.17e-38,1), -l1 in [5.9e-8, 88.8]). rel err ~1e-12 —
// far inside the f32-rounding safety margin. Validated bit-exact vs ref.
__device__ __forceinline__ double flog(double x) {
  long long bits = __double_as_longlong(x);
  int e = (int)(bits >> 52) - 1023;
  double m = __longlong_as_double((bits & 0x000fffffffffffffLL) |
                                  0x3ff0000000000000LL);   // [1,2)
  if (m > 1.4142135623730951) { m *= 0.5; e += 1; }
  double mp1 = m + 1.0;
  double r = __builtin_amdgcn_rcp(mp1);            // v_rcp_f64, ~2^-29
  r = r * __builtin_fma(-mp1, r, 2.0);             // NR1
  r = r * __builtin_fma(-mp1, r, 2.0);             // NR2 -> ~1 ulp f64
  double z = (m - 1.0) * r;              // |z| <= 0.1716
  double w = z * z;                      // <= 0.02944
  double p = 1.0 / 15.0;
  p = __builtin_fma(p, w, 1.0 / 13.0);
  p = __builtin_fma(p, w, 1.0 / 11.0);
  p = __builtin_fma(p, w, 1.0 / 9.0);
  p = __builtin_fma(p, w, 1.0 / 7.0);
  p = __builtin_fma(p, w, 1.0 / 5.0);
  p = __builtin_fma(p, w, 1.0 / 3.0);
  p = __builtin_fma(p, w, 1.0);
  double de = (double)e;
  const double ln2_hi = 6.93147180369123816490e-01;  // low bits zero
  const double ln2_lo = 1.90821492927058770002e-10;
  return __builtin_fma(de, ln2_hi,
                       __builtin_fma(2.0 * z, p, de * ln2_lo));
}

__device__ __forceinline__ float gumbel_from_u32(uint32_t bits) {
  uint32_t fb = (bits >> 9) | 0x3f800000u;
  float f = __uint_as_float(fb) - 1.0f;          // [0,1), exact
  float u = (f > 0.0f) ? f : 1.17549435e-38f;    // JAX uniform(minval=tiny)
  float l1 = (float)flog((double)u);
  float l2 = (float)flog((double)(-l1));
  return -l2;
}

// -------- fast path: f32 log, certified bound (guard use only) --------
// For normal positive x. Error analysis:
//   m-1 exact (Sterbenz, m in [0.707,1.414]); rcp_f32 rel ~1e-7;
//   poly trunc rel ~3.6e-6 (w^3/7 term); f32 roundings ~4e-7.
//   => rel err(ln x) <= ~6e-6 when no cancellation; near x->1 the z-form
//   keeps it relative (~1e-7). Through g=-ln(-ln u): abs err on g
//   <= rel(l1) + rel_alg*|l2| <= ~1e-4 worst (u->1, |l2|~16), 3.5e-5 typ.
__device__ __forceinline__ float fast_ln(float x) {
  uint32_t b = __float_as_uint(x);
  int e = (int)(b >> 23) - 127;
  float m = __uint_as_float((b & 0x007fffffu) | 0x3f800000u);  // [1,2)
  if (m > 1.41421356f) { m *= 0.5f; e += 1; }
  float z = (m - 1.0f) * __builtin_amdgcn_rcpf(m + 1.0f);  // |z|<=0.1716
  float w = z * z;
  float p = __builtin_fmaf(w, __builtin_fmaf(w, 0.14285715f, 0.2f),
                           0.33333334f);
  float q = __builtin_fmaf(w, p, 1.0f);
  float lnm = 2.0f * z * q;
  return __builtin_fmaf((float)e, 0.69314718f, lnm);
}

__device__ __forceinline__ float gumbel_fast(uint32_t bits) {
  uint32_t fb = (bits >> 9) | 0x3f800000u;
  float f = __uint_as_float(fb) - 1.0f;
  float u = (f > 0.0f) ? f : 1.17549435e-38f;
  float l1 = fast_ln(u);        // < 0 always (|l1| >= ~1.19e-7)
  return -fast_ln(-l1);
}

// guard threshold: covers 2x certified gumbel error + f32 add-rounding
// (2^-23 * |t| terms) with >=5x margin on the constant, ~250x on the slope.
__device__ __forceinline__ float guard_tau(float a, float b) {
  return 1e-3f + 3.1e-5f * (fabsf(a) + fabsf(b));
}

// -------- edge selection for BOTH layers (+ fused op selection) --------
__global__ __launch_bounds__(256) void edges_kernel(
    const float* __restrict__ etcA, const float* __restrict__ otcA,
    uint32_t oa0, uint32_t oa1, uint32_t ea0, uint32_t ea1,
    int* __restrict__ opA, unsigned long long* __restrict__ selA,
    const float* __restrict__ etcB, const float* __restrict__ otcB,
    uint32_t ob0, uint32_t ob1, uint32_t eb0, uint32_t eb1,
    int* __restrict__ opB, unsigned long long* __restrict__ selB) {
  int gid = blockIdx.x * 256 + threadIdx.x;
  const float *etc, *otc; unsigned long long* selw; int* opx;
  uint32_t ok0, ok1, k0, k1; int inlog;
  if (gid < 512 * 1024) {
    etc = etcA; otc = otcA; opx = opA; selw = selA;
    ok0 = oa0; ok1 = oa1; k0 = ea0; k1 = ea1; inlog = 10;
  } else {
    gid -= 512 * 1024;
    etc = etcB; otc = otcB; opx = opB; selw = selB;
    ok0 = ob0; ok1 = ob1; k0 = eb0; k1 = eb1; inlog = 9;
  }
  int o = gid >> inlog;
  int lane = threadIdx.x & 63;

  // ---- op selection: guarded fast path (deterministic across all waves
  //      of the same o, so opx stores stay consistent) ----
  float vf = 0.0f;
  if (lane < 2)
    vf = otc[2 * o + lane] +
         gumbel_fast(rbits32(ok0, ok1, (uint32_t)(2 * o + lane)));
  float v0 = __shfl(vf, 0, 64);
  float v1 = __shfl(vf, 1, 64);
  float dop = v1 - v0;
  int j;
  if (__builtin_expect(fabsf(dop) <= guard_tau(v0, v1), 0)) {
    float ve0 = otc[2 * o] +
                gumbel_from_u32(rbits32(ok0, ok1, (uint32_t)(2 * o)));
    float ve1 = otc[2 * o + 1] +
                gumbel_from_u32(rbits32(ok0, ok1, (uint32_t)(2 * o + 1)));
    j = (ve1 > ve0) ? 1 : 0;   // argmax, tie->0 (exact)
  } else {
    j = (dop > 0.0f) ? 1 : 0;
  }
  if (threadIdx.x == 0) opx[o] = j;

  // ---- edge selection: guarded fast path ----
  int i = gid & ((1 << inlog) - 1);
  uint32_t e0 = (uint32_t)((((o * 2 + j) << inlog) + i) * 2);
  uint32_t r0 = rbits32(k0, k1, e0);
  uint32_t r1 = rbits32(k0, k1, e0 + 1u);
  const float* c = etc + (size_t)e0;              // etc flat idx == e0
  float c0 = c[0], c1 = c[1];
  float t0 = c0 + gumbel_fast(r0);
  float t1 = c1 + gumbel_fast(r1);
  float diff = t1 - t0;
  bool sel;
  if (__builtin_expect(fabsf(diff) <= guard_tau(t0, t1), 0)) {
    // rare (~6e-4/lane): bit-exact recompute with the SAME threefry bits
    sel = (c1 + gumbel_from_u32(r1)) > (c0 + gumbel_from_u32(r0));
  } else {
    sel = diff > 0.0f;
  }
  unsigned long long m = __ballot(sel ? 1 : 0);
  if (lane == 0) selw[gid >> 6] = m;
}

// -------- layer forward: one wave per (b, 8 consecutive o) --------
// Sign trick: min(v) = -max(-v). op=0(min): s=-1, neutral=-1, negate at end.
// Mask access is u32-granular (little-endian low word first == bits 0..31
// of the u64), with the per-lane shift hoisted out of the loops.
template <int IN_F, int OUT_F>
__global__ __launch_bounds__(256) void forward_kernel(
    const float* __restrict__ x, const int* __restrict__ opidx,
    const unsigned long long* __restrict__ selw, float* __restrict__ out) {
  constexpr int W32 = IN_F / 32;              // u32 mask words per o
  constexpr int CH = IN_F / 256;              // chunks of 256 floats
  const uint32_t* __restrict__ sel32 = (const uint32_t*)selw;
  int wave = blockIdx.x * 4 + (threadIdx.x >> 6);
  int lane = threadIdx.x & 63;
  int og = wave % (OUT_F / 8);
  int b  = wave / (OUT_F / 8);
  int o0 = og * 8;
  int sh = (lane * 4) & 31;                   // nibble shift within u32
  int wb = lane >> 3;                         // (lane*4)>>5

  float sgn[8], neu[8];
  int opv[8];
#pragma unroll
  for (int jj = 0; jj < 8; ++jj) {
    int op = opidx[o0 + jj];
    opv[jj] = op;
    sgn[jj] = op ? 1.0f : -1.0f;
    neu[jj] = op ? 0.0f : -1.0f;
  }
  float acc[8];
#pragma unroll
  for (int jj = 0; jj < 8; ++jj) acc[jj] = -1e30f;
  const float* xrow = x + (size_t)b * IN_F;
#pragma unroll
  for (int cc = 0; cc < CH; ++cc) {
    int i0 = cc * 256 + lane * 4;
    float4 xv = *(const float4*)(xrow + i0);
    int w32 = cc * 8 + wb;
#pragma unroll
    for (int jj = 0; jj < 8; ++jj) {
      uint32_t m32 = sel32[(o0 + jj) * W32 + w32];
      uint32_t b4 = (m32 >> sh) & 0xFu;
      float s = sgn[jj], n = neu[jj];
      float v0 = (b4 & 1u) ? s * xv.x : n;
      float v1 = (b4 & 2u) ? s * xv.y : n;
      float v2 = (b4 & 4u) ? s * xv.z : n;
      float v3 = (b4 & 8u) ? s * xv.w : n;
      acc[jj] = fmaxf(acc[jj], fmaxf(fmaxf(v0, v1), fmaxf(v2, v3)));
    }
  }
#pragma unroll
  for (int d = 1; d < 64; d <<= 1) {
#pragma unroll
    for (int jj = 0; jj < 8; ++jj)
      acc[jj] = fmaxf(acc[jj], __shfl_xor(acc[jj], d, 64));
  }
  if (lane == 0) {
    float4 r0, r1;
    r0.x = opv[0] ? acc[0] : -acc[0];
    r0.y = opv[1] ? acc[1] : -acc[1];
    r0.z = opv[2] ? acc[2] : -acc[2];
    r0.w = opv[3] ? acc[3] : -acc[3];
    r1.x = opv[4] ? acc[4] : -acc[4];
    r1.y = opv[5] ? acc[5] : -acc[5];
    r1.z = opv[6] ? acc[6] : -acc[6];
    r1.w = opv[7] ? acc[7] : -acc[7];
    float* op = out + (size_t)b * OUT_F + o0;
    *(float4*)op = r0;
    *(float4*)(op + 4) = r1;
  }
}

extern "C" void kernel_launch(void* const* d_in, const int* in_sizes, int n_in,
                              void* d_out, int out_size, void* d_ws, size_t ws_size,
                              hipStream_t stream) {
  const float* x    = (const float*)d_in[0];   // [128,1024]
  const float* etc0 = (const float*)d_in[1];   // [512,2,1024,2]
  const float* otc0 = (const float*)d_in[2];   // [512,2]
  const float* etc1 = (const float*)d_in[3];   // [1024,2,512,2]
  const float* otc1 = (const float*)d_in[4];   // [1024,2]
  float* out = (float*)d_out;                  // [128,1024] f32

  // ---- host-side key derivation (pure CPU, graph-capture safe) ----
  uint32_t K0a, K0b, K1a, K1b;
  threefry2x32(0u, 42u, 0u, 0u, &K0a, &K0b);   // fold_in(key(42), 0)
  threefry2x32(0u, 42u, 0u, 1u, &K1a, &K1b);   // fold_in(key(42), 1)
  uint32_t op0k0, op0k1, ed0k0, ed0k1;
  threefry2x32(K0a, K0b, 0u, 0u, &op0k0, &op0k1);
  threefry2x32(K0a, K0b, 0u, 1u, &ed0k0, &ed0k1);
  uint32_t op1k0, op1k1, ed1k0, ed1k1;
  threefry2x32(K1a, K1b, 0u, 0u, &op1k0, &op1k1);
  threefry2x32(K1a, K1b, 0u, 1u, &ed1k0, &ed1k1);

  // ---- workspace layout ----
  char* wsb = (char*)d_ws;
  int* opidx0 = (int*)wsb;                                        // 512 ints
  int* opidx1 = (int*)(wsb + 2048);                               // 1024 ints
  unsigned long long* selw0 = (unsigned long long*)(wsb + 8192);  // 512*16 u64
  unsigned long long* selw1 = (unsigned long long*)(wsb + 8192 + 65536); // 1024*8
  float* h = (float*)(wsb + 8192 + 131072);                       // 128*512 f32

  hipLaunchKernelGGL(edges_kernel, dim3(4096), dim3(256), 0, stream,
                     etc0, otc0, op0k0, op0k1, ed0k0, ed0k1, opidx0, selw0,
                     etc1, otc1, op1k0, op1k1, ed1k0, ed1k1, opidx1, selw1);
  hipLaunchKernelGGL((forward_kernel<1024, 512>), dim3(2048), dim3(256), 0,
                     stream, x, opidx0, selw0, h);
  hipLaunchKernelGGL((forward_kernel<512, 1024>), dim3(4096), dim3(256), 0,
                     stream, h, opidx1, selw1, out);
}

// Round 2
// 99.757 us; speedup vs baseline: 1.1409x; 1.0450x over previous
//
#include <hip/hip_runtime.h>
#include <stdint.h>

// FFEdgeCountingAutoencoder4: two "fuzzy logic" layers.
// Randomness: JAX threefry2x32, PARTITIONABLE counter semantics:
//   bits(e) = o0 ^ o1 of threefry(key, (0, e)).   (verified: absmax == 0.0)
// Keys host-side: base=key(42)=(0,42); K_l=tf(base,(0,l));
//   split: k_op=tf(K,(0,0)), k_edge=tf(K,(0,1)).
// Gumbel: u = max(tiny, ((bits>>9)|0x3f800000 as float)-1); g=-log(-log u).
//
// Decision hierarchy for argmax comparisons (all bit-exact by construction):
//  1) INTEGER path (runtime-checked c0==c1): gumbel is strictly monotone in
//     (bits>>9). Min slope per grid step = e*2^-23 = 3.24e-7 (at u=1/e).
//     Two-stage f32 log rounding fuzz <= (1+16.65)*2^-24 per point -> ~6.5
//     steps for two points. Add-rounding needs dg > ulp(c+g) <=
//     (|c|+16)*2^-23. Threshold T = 8 + 3*(|c|+16) steps (>=8x margin on the
//     add term). |gap| >= T -> decide by sign(gap). Else fall to (2).
//  2) f32 fast-log path with certified guard tau (validated rounds 1-2).
//  3) exact f64-log path (validated bit-exact vs ref since round 0).
// Ties (gap==0, equal gumbels) always land in (3) -> argmax tie->0 exact.

__host__ __device__ inline uint32_t rotl32(uint32_t x, uint32_t d) {
  return (x << d) | (x >> (32u - d));
}

__host__ __device__ inline void threefry2x32(uint32_t k0, uint32_t k1,
                                             uint32_t x0, uint32_t x1,
                                             uint32_t* o0, uint32_t* o1) {
  uint32_t ks0 = k0, ks1 = k1, ks2 = k0 ^ k1 ^ 0x1BD11BDAu;
  x0 += ks0; x1 += ks1;
#define TF_R(r) { x0 += x1; x1 = rotl32(x1, r); x1 ^= x0; }
  TF_R(13u) TF_R(15u) TF_R(26u) TF_R(6u)
  x0 += ks1; x1 += ks2 + 1u;
  TF_R(17u) TF_R(29u) TF_R(16u) TF_R(24u)
  x0 += ks2; x1 += ks0 + 2u;
  TF_R(13u) TF_R(15u) TF_R(26u) TF_R(6u)
  x0 += ks0; x1 += ks1 + 3u;
  TF_R(17u) TF_R(29u) TF_R(16u) TF_R(24u)
  x0 += ks1; x1 += ks2 + 4u;
  TF_R(13u) TF_R(15u) TF_R(26u) TF_R(6u)
  x0 += ks2; x1 += ks0 + 5u;
#undef TF_R
  *o0 = x0; *o1 = x1;
}

__device__ __forceinline__ uint32_t rbits32(uint32_t k0, uint32_t k1,
                                            uint32_t e) {
  uint32_t a, b;
  threefry2x32(k0, k1, 0u, e, &a, &b);
  return a ^ b;
}

// -------- exact path: f64 log for normal positive finite x --------
__device__ __forceinline__ double flog(double x) {
  long long bits = __double_as_longlong(x);
  int e = (int)(bits >> 52) - 1023;
  double m = __longlong_as_double((bits & 0x000fffffffffffffLL) |
                                  0x3ff0000000000000LL);   // [1,2)
  if (m > 1.4142135623730951) { m *= 0.5; e += 1; }
  double mp1 = m + 1.0;
  double r = __builtin_amdgcn_rcp(mp1);            // v_rcp_f64, ~2^-29
  r = r * __builtin_fma(-mp1, r, 2.0);             // NR1
  r = r * __builtin_fma(-mp1, r, 2.0);             // NR2 -> ~1 ulp f64
  double z = (m - 1.0) * r;              // |z| <= 0.1716
  double w = z * z;                      // <= 0.02944
  double p = 1.0 / 15.0;
  p = __builtin_fma(p, w, 1.0 / 13.0);
  p = __builtin_fma(p, w, 1.0 / 11.0);
  p = __builtin_fma(p, w, 1.0 / 9.0);
  p = __builtin_fma(p, w, 1.0 / 7.0);
  p = __builtin_fma(p, w, 1.0 / 5.0);
  p = __builtin_fma(p, w, 1.0 / 3.0);
  p = __builtin_fma(p, w, 1.0);
  double de = (double)e;
  const double ln2_hi = 6.93147180369123816490e-01;  // low bits zero
  const double ln2_lo = 1.90821492927058770002e-10;
  return __builtin_fma(de, ln2_hi,
                       __builtin_fma(2.0 * z, p, de * ln2_lo));
}

__device__ __forceinline__ float gumbel_from_u32(uint32_t bits) {
  uint32_t fb = (bits >> 9) | 0x3f800000u;
  float f = __uint_as_float(fb) - 1.0f;          // [0,1), exact
  float u = (f > 0.0f) ? f : 1.17549435e-38f;    // JAX uniform(minval=tiny)
  float l1 = (float)flog((double)u);
  float l2 = (float)flog((double)(-l1));
  return -l2;
}

// -------- f32 fast-log path (certified bound, guard use only) --------
__device__ __forceinline__ float fast_ln(float x) {
  uint32_t b = __float_as_uint(x);
  int e = (int)(b >> 23) - 127;
  float m = __uint_as_float((b & 0x007fffffu) | 0x3f800000u);  // [1,2)
  if (m > 1.41421356f) { m *= 0.5f; e += 1; }
  float z = (m - 1.0f) * __builtin_amdgcn_rcpf(m + 1.0f);  // |z|<=0.1716
  float w = z * z;
  float p = __builtin_fmaf(w, __builtin_fmaf(w, 0.14285715f, 0.2f),
                           0.33333334f);
  float q = __builtin_fmaf(w, p, 1.0f);
  float lnm = 2.0f * z * q;
  return __builtin_fmaf((float)e, 0.69314718f, lnm);
}

__device__ __forceinline__ float gumbel_fast(uint32_t bits) {
  uint32_t fb = (bits >> 9) | 0x3f800000u;
  float f = __uint_as_float(fb) - 1.0f;
  float u = (f > 0.0f) ? f : 1.17549435e-38f;
  float l1 = fast_ln(u);        // < 0 always (|l1| >= ~1.19e-7)
  return -fast_ln(-l1);
}

__device__ __forceinline__ float guard_tau(float a, float b) {
  return 1e-3f + 3.1e-5f * (fabsf(a) + fabsf(b));
}

// (c1+g(r1)) > (c0+g(r0)) with ref's f32 rounding: exact f64 path.
__device__ __noinline__ bool sel_exact(float c0, float c1,
                                       uint32_t r0, uint32_t r1) {
  return (c1 + gumbel_from_u32(r1)) > (c0 + gumbel_from_u32(r0));
}

// Guarded f32 fast path, f64 fallback on near-tie. Bit-exact.
__device__ __forceinline__ bool sel_guarded(float c0, float c1,
                                            uint32_t r0, uint32_t r1) {
  float t0 = c0 + gumbel_fast(r0);
  float t1 = c1 + gumbel_fast(r1);
  float diff = t1 - t0;
  if (__builtin_expect(fabsf(diff) <= guard_tau(t0, t1), 0))
    return sel_exact(c0, c1, r0, r1);
  return diff > 0.0f;
}

// Top-level compare: integer shortcut when counts are bitwise equal.
__device__ __forceinline__ bool sel_cmp(float c0, float c1,
                                        uint32_t r0, uint32_t r1) {
  if (__builtin_expect(c0 == c1, 1)) {
    int gap = (int)(r1 >> 9) - (int)(r0 >> 9);
    int T = 8 + (int)((fabsf(c0) + 16.0f) * 3.0f);   // certified threshold
    if (__builtin_expect(gap >= T || gap <= -T, 1)) return gap > 0;
    return sel_guarded(c0, c1, r0, r1);              // rare (~1.4e-5)
  }
  return sel_guarded(c0, c1, r0, r1);
}

// -------- edge + op selection for BOTH layers --------
// Blocks 0..511: layer A, one block per o; wave w covers i in [256w,256w+256).
// Blocks 512..1023: layer B, block per 2 o's; wave pair covers 512 i of one o.
// Each thread handles 4 edge pairs (i = ibase + 64p + lane), so the op-draw
// prefix and prologue are amortized 4x; ballot word = i/64 directly.
__global__ __launch_bounds__(256) void edges_kernel(
    const float* __restrict__ etcA, const float* __restrict__ otcA,
    uint32_t oa0, uint32_t oa1, uint32_t ea0, uint32_t ea1,
    int* __restrict__ opA, unsigned long long* __restrict__ selA,
    const float* __restrict__ etcB, const float* __restrict__ otcB,
    uint32_t ob0, uint32_t ob1, uint32_t eb0, uint32_t eb1,
    int* __restrict__ opB, unsigned long long* __restrict__ selB) {
  int widx = threadIdx.x >> 6;
  int lane = threadIdx.x & 63;
  const float *etc, *otc; unsigned long long* selw; int* opx;
  uint32_t ok0, ok1, k0, k1;
  int inlog, o, ibase, wordbase;
  bool store_op;
  if (blockIdx.x < 512) {
    etc = etcA; otc = otcA; opx = opA; selw = selA;
    ok0 = oa0; ok1 = oa1; k0 = ea0; k1 = ea1; inlog = 10;
    o = blockIdx.x;
    ibase = widx * 256;
    wordbase = o * 16 + widx * 4;
    store_op = (threadIdx.x == 0);
  } else {
    etc = etcB; otc = otcB; opx = opB; selw = selB;
    ok0 = ob0; ok1 = ob1; k0 = eb0; k1 = eb1; inlog = 9;
    int bb = blockIdx.x - 512;
    o = bb * 2 + (widx >> 1);
    ibase = (widx & 1) * 256;
    wordbase = o * 8 + (widx & 1) * 4;
    store_op = ((widx & 1) == 0) && (lane == 0);
  }

  // ---- op selection (lanes 0,1 draw; all lanes decide identically) ----
  uint32_t rop = 0; float cop = 0.0f;
  if (lane < 2) {
    rop = rbits32(ok0, ok1, (uint32_t)(2 * o + lane));
    cop = otc[2 * o + lane];
  }
  uint32_t rop0 = (uint32_t)__shfl((int)rop, 0, 64);
  uint32_t rop1 = (uint32_t)__shfl((int)rop, 1, 64);
  float cop0 = __shfl(cop, 0, 64);
  float cop1 = __shfl(cop, 1, 64);
  int j = sel_cmp(cop0, cop1, rop0, rop1) ? 1 : 0;
  if (store_op) opx[o] = j;

  // ---- edge selection: 4 pairs per thread ----
  uint32_t ebase = (uint32_t)((o * 2 + j) << (inlog + 1));
  const float* cbase = etc + (size_t)ebase;
  bool selv[4];
#pragma unroll
  for (int p = 0; p < 4; ++p) {
    int i = ibase + p * 64 + lane;
    uint32_t e0 = ebase + (uint32_t)(2 * i);
    uint32_t r0 = rbits32(k0, k1, e0);
    uint32_t r1 = rbits32(k0, k1, e0 + 1u);
    float2 cc = *(const float2*)(cbase + 2 * i);
    selv[p] = sel_cmp(cc.x, cc.y, r0, r1);
  }
#pragma unroll
  for (int p = 0; p < 4; ++p) {
    unsigned long long m = __ballot(selv[p] ? 1 : 0);
    if (lane == 0) selw[wordbase + p] = m;
  }
}

// -------- layer forward: one wave per (b, 8 consecutive o) --------
// Sign trick: min(v) = -max(-v). op=0(min): s=-1, neutral=-1, negate at end.
template <int IN_F, int OUT_F>
__global__ __launch_bounds__(256) void forward_kernel(
    const float* __restrict__ x, const int* __restrict__ opidx,
    const unsigned long long* __restrict__ selw, float* __restrict__ out) {
  constexpr int W32 = IN_F / 32;              // u32 mask words per o
  constexpr int CH = IN_F / 256;              // chunks of 256 floats
  const uint32_t* __restrict__ sel32 = (const uint32_t*)selw;
  int wave = blockIdx.x * 4 + (threadIdx.x >> 6);
  int lane = threadIdx.x & 63;
  int og = wave % (OUT_F / 8);
  int b  = wave / (OUT_F / 8);
  int o0 = og * 8;
  int sh = (lane * 4) & 31;                   // nibble shift within u32
  int wb = lane >> 3;                         // (lane*4)>>5

  float sgn[8], neu[8];
  int opv[8];
#pragma unroll
  for (int jj = 0; jj < 8; ++jj) {
    int op = opidx[o0 + jj];
    opv[jj] = op;
    sgn[jj] = op ? 1.0f : -1.0f;
    neu[jj] = op ? 0.0f : -1.0f;
  }
  float acc[8];
#pragma unroll
  for (int jj = 0; jj < 8; ++jj) acc[jj] = -1e30f;
  const float* xrow = x + (size_t)b * IN_F;
#pragma unroll
  for (int cc = 0; cc < CH; ++cc) {
    int i0 = cc * 256 + lane * 4;
    float4 xv = *(const float4*)(xrow + i0);
    int w32 = cc * 8 + wb;
#pragma unroll
    for (int jj = 0; jj < 8; ++jj) {
      uint32_t m32 = sel32[(o0 + jj) * W32 + w32];
      uint32_t b4 = (m32 >> sh) & 0xFu;
      float s = sgn[jj], n = neu[jj];
      float v0 = (b4 & 1u) ? s * xv.x : n;
      float v1 = (b4 & 2u) ? s * xv.y : n;
      float v2 = (b4 & 4u) ? s * xv.z : n;
      float v3 = (b4 & 8u) ? s * xv.w : n;
      acc[jj] = fmaxf(acc[jj], fmaxf(fmaxf(v0, v1), fmaxf(v2, v3)));
    }
  }
#pragma unroll
  for (int d = 1; d < 64; d <<= 1) {
#pragma unroll
    for (int jj = 0; jj < 8; ++jj)
      acc[jj] = fmaxf(acc[jj], __shfl_xor(acc[jj], d, 64));
  }
  if (lane == 0) {
    float4 r0, r1;
    r0.x = opv[0] ? acc[0] : -acc[0];
    r0.y = opv[1] ? acc[1] : -acc[1];
    r0.z = opv[2] ? acc[2] : -acc[2];
    r0.w = opv[3] ? acc[3] : -acc[3];
    r1.x = opv[4] ? acc[4] : -acc[4];
    r1.y = opv[5] ? acc[5] : -acc[5];
    r1.z = opv[6] ? acc[6] : -acc[6];
    r1.w = opv[7] ? acc[7] : -acc[7];
    float* op = out + (size_t)b * OUT_F + o0;
    *(float4*)op = r0;
    *(float4*)(op + 4) = r1;
  }
}

extern "C" void kernel_launch(void* const* d_in, const int* in_sizes, int n_in,
                              void* d_out, int out_size, void* d_ws, size_t ws_size,
                              hipStream_t stream) {
  const float* x    = (const float*)d_in[0];   // [128,1024]
  const float* etc0 = (const float*)d_in[1];   // [512,2,1024,2]
  const float* otc0 = (const float*)d_in[2];   // [512,2]
  const float* etc1 = (const float*)d_in[3];   // [1024,2,512,2]
  const float* otc1 = (const float*)d_in[4];   // [1024,2]
  float* out = (float*)d_out;                  // [128,1024] f32

  // ---- host-side key derivation (pure CPU, graph-capture safe) ----
  uint32_t K0a, K0b, K1a, K1b;
  threefry2x32(0u, 42u, 0u, 0u, &K0a, &K0b);   // fold_in(key(42), 0)
  threefry2x32(0u, 42u, 0u, 1u, &K1a, &K1b);   // fold_in(key(42), 1)
  uint32_t op0k0, op0k1, ed0k0, ed0k1;
  threefry2x32(K0a, K0b, 0u, 0u, &op0k0, &op0k1);
  threefry2x32(K0a, K0b, 0u, 1u, &ed0k0, &ed0k1);
  uint32_t op1k0, op1k1, ed1k0, ed1k1;
  threefry2x32(K1a, K1b, 0u, 0u, &op1k0, &op1k1);
  threefry2x32(K1a, K1b, 0u, 1u, &ed1k0, &ed1k1);

  // ---- workspace layout ----
  char* wsb = (char*)d_ws;
  int* opidx0 = (int*)wsb;                                        // 512 ints
  int* opidx1 = (int*)(wsb + 2048);                               // 1024 ints
  unsigned long long* selw0 = (unsigned long long*)(wsb + 8192);  // 512*16 u64
  unsigned long long* selw1 = (unsigned long long*)(wsb + 8192 + 65536); // 1024*8
  float* h = (float*)(wsb + 8192 + 131072);                       // 128*512 f32

  hipLaunchKernelGGL(edges_kernel, dim3(1024), dim3(256), 0, stream,
                     etc0, otc0, op0k0, op0k1, ed0k0, ed0k1, opidx0, selw0,
                     etc1, otc1, op1k0, op1k1, ed1k0, ed1k1, opidx1, selw1);
  hipLaunchKernelGGL((forward_kernel<1024, 512>), dim3(2048), dim3(256), 0,
                     stream, x, opidx0, selw0, h);
  hipLaunchKernelGGL((forward_kernel<512, 1024>), dim3(4096), dim3(256), 0,
                     stream, h, opidx1, selw1, out);
}